// Round 1
// baseline (722.830 us; speedup 1.0000x reference)
//
#include <hip/hip_runtime.h>

#define KG 256      // gaussians
#define DD 12       // feature dim
#define HH 32       // hidden
#define CC 9        // output channels
#define CHUNK 32    // k-chunk staged in LDS per flush
#define AST 32      // floats per packed gaussian record

// Per-gaussian precompute: fold precision quadratic form into a polynomial in
// probe-pos monomials, pre-scaled by -0.5*log2(e) so g = exp2(poly).
// Record layout (32 floats): [0..9] mahal-poly coeffs (xx,yy,zz,xy,xz,yz,x,y,z,1)
// [10..13] dist2 coeffs (x,y,z,1; dist2 = s3 + these) [14] r^2 [15] pad
// [16..27] F row [28..31] pad
__global__ __launch_bounds__(256) void gp_precompute(
    const float* __restrict__ mu, const float* __restrict__ log_s,
    const float* __restrict__ q, const float* __restrict__ F,
    float* __restrict__ A) {
  int k = threadIdx.x;
  if (k >= KG) return;
  float qw = q[k*4+0], qx = q[k*4+1], qy = q[k*4+2], qz = q[k*4+3];
  float nrm = sqrtf(qw*qw + qx*qx + qy*qy + qz*qz);
  float isn = 1.0f / (nrm + 1e-8f);
  qw *= isn; qx *= isn; qy *= isn; qz *= isn;
  float R00 = 1.f - 2.f*(qy*qy + qz*qz);
  float R01 = 2.f*(qx*qy - qw*qz);
  float R02 = 2.f*(qx*qz + qw*qy);
  float R10 = 2.f*(qx*qy + qw*qz);
  float R11 = 1.f - 2.f*(qx*qx + qz*qz);
  float R12 = 2.f*(qy*qz - qw*qx);
  float R20 = 2.f*(qx*qz - qw*qy);
  float R21 = 2.f*(qy*qz + qw*qx);
  float R22 = 1.f - 2.f*(qx*qx + qy*qy);
  float s0 = expf(log_s[k*3+0]);
  float s1 = expf(log_s[k*3+1]);
  float s2 = expf(log_s[k*3+2]);
  float si0 = 1.f/(s0*s0 + 1e-8f);
  float si1 = 1.f/(s1*s1 + 1e-8f);
  float si2 = 1.f/(s2*s2 + 1e-8f);
  // P = R diag(si) R^T (symmetric)
  float P00 = R00*si0*R00 + R01*si1*R01 + R02*si2*R02;
  float P01 = R00*si0*R10 + R01*si1*R11 + R02*si2*R12;
  float P02 = R00*si0*R20 + R01*si1*R21 + R02*si2*R22;
  float P11 = R10*si0*R10 + R11*si1*R11 + R12*si2*R12;
  float P12 = R10*si0*R20 + R11*si1*R21 + R12*si2*R22;
  float P22 = R20*si0*R20 + R21*si1*R21 + R22*si2*R22;
  float m0 = mu[k*3+0], m1 = mu[k*3+1], m2 = mu[k*3+2];
  // mahal(pos) = pos^T P pos - 2 (P mu).pos + mu^T P mu
  float b0 = P00*m0 + P01*m1 + P02*m2;
  float b1v = P01*m0 + P11*m1 + P12*m2;
  float b2v = P02*m0 + P12*m1 + P22*m2;
  float c = m0*b0 + m1*b1v + m2*b2v;
  const float f = -0.7213475204444817f;  // -0.5*log2(e)
  float* Ak = A + k*AST;
  Ak[0] = f*P00; Ak[1] = f*P11; Ak[2] = f*P22;
  Ak[3] = 2.f*f*P01; Ak[4] = 2.f*f*P02; Ak[5] = 2.f*f*P12;
  Ak[6] = -2.f*f*b0; Ak[7] = -2.f*f*b1v; Ak[8] = -2.f*f*b2v;
  Ak[9] = f*c;
  Ak[10] = -2.f*m0; Ak[11] = -2.f*m1; Ak[12] = -2.f*m2;
  Ak[13] = m0*m0 + m1*m1 + m2*m2;
  float smax = fmaxf(s0, fmaxf(s1, s2));
  float r = 3.f*smax;
  Ak[14] = r*r;
  Ak[15] = 0.f;
  #pragma unroll
  for (int d = 0; d < DD; d++) Ak[16+d] = F[k*DD+d];
  Ak[28] = Ak[29] = Ak[30] = Ak[31] = 0.f;
}

__global__ __launch_bounds__(256) void gp_main(
    const float* __restrict__ pos, const float* __restrict__ A,
    const float* __restrict__ W1, const float* __restrict__ b1,
    const float* __restrict__ W2, const float* __restrict__ b2,
    float* __restrict__ sh_out, float* __restrict__ lat_out,
    float* __restrict__ w_out, int N) {
  // padded stage: row stride 33 floats -> writes land tid%32 banks (2-way, free),
  // flush reads (pp*33+kl)%32 distinct banks. 33.8 KB -> 4 blocks/CU.
  __shared__ float stage[256*(CHUNK+1)];
  const int tid = threadIdx.x;
  const int pbase = blockIdx.x * 256;
  const int p = pbase + tid;
  const bool valid = p < N;
  float x = 0.f, y = 0.f, z = 0.f;
  if (valid) { x = pos[p*3+0]; y = pos[p*3+1]; z = pos[p*3+2]; }
  const float xx = x*x, yy = y*y, zz = z*z, xy = x*y, xz = x*z, yz = y*z;
  const float s3 = xx + yy + zz;

  // ---- pass 1: denominator ----
  float sum = 0.f;
  #pragma unroll 8
  for (int k = 0; k < KG; k++) {
    const float* Ak = A + k*AST;   // uniform index -> scalar loads
    float t = Ak[9] + Ak[0]*xx + Ak[1]*yy + Ak[2]*zz
            + Ak[3]*xy + Ak[4]*xz + Ak[5]*yz
            + Ak[6]*x + Ak[7]*y + Ak[8]*z;
    float d2 = s3 + Ak[13] + Ak[10]*x + Ak[11]*y + Ak[12]*z;
    float g = (d2 < Ak[14]) ? exp2f(t) : 0.f;
    sum += g;
  }
  const float inv = 1.f/(sum + 1e-8f);

  // ---- pass 2: recompute, normalize, stage+flush weights, accumulate latent ----
  float lat[DD];
  #pragma unroll
  for (int j = 0; j < DD; j++) lat[j] = 0.f;

  for (int c0 = 0; c0 < KG; c0 += CHUNK) {
    #pragma unroll 4
    for (int kl = 0; kl < CHUNK; kl++) {
      const int k = c0 + kl;
      const float* Ak = A + k*AST;
      float t = Ak[9] + Ak[0]*xx + Ak[1]*yy + Ak[2]*zz
              + Ak[3]*xy + Ak[4]*xz + Ak[5]*yz
              + Ak[6]*x + Ak[7]*y + Ak[8]*z;
      float d2 = s3 + Ak[13] + Ak[10]*x + Ak[11]*y + Ak[12]*z;
      float g = (d2 < Ak[14]) ? exp2f(t) : 0.f;
      float w = g * inv;
      stage[tid*(CHUNK+1) + kl] = w;
      #pragma unroll
      for (int j = 0; j < DD; j++) lat[j] += w * Ak[16+j];
    }
    __syncthreads();
    // cooperative coalesced flush: consecutive lanes -> consecutive k of one probe
    #pragma unroll
    for (int i = 0; i < CHUNK; i++) {
      int idx = i*256 + tid;
      int pp = idx >> 5;            // idx / CHUNK
      int kl = idx & (CHUNK-1);
      int gp = pbase + pp;
      if (gp < N) w_out[(size_t)gp*KG + c0 + kl] = stage[pp*(CHUNK+1) + kl];
    }
    __syncthreads();
  }

  // ---- latent out (3x float4, 16B-aligned: base offset N*9*4 = 7.2e6 B, stride 48B) ----
  if (valid) {
    float4* lp = (float4*)(lat_out + (size_t)p*DD);
    lp[0] = make_float4(lat[0], lat[1], lat[2],  lat[3]);
    lp[1] = make_float4(lat[4], lat[5], lat[6],  lat[7]);
    lp[2] = make_float4(lat[8], lat[9], lat[10], lat[11]);
  }

  // ---- fused MLP (weights uniform -> scalar loads) ----
  float in15[15];
  #pragma unroll
  for (int j = 0; j < DD; j++) in15[j] = lat[j];
  in15[12] = x; in15[13] = y; in15[14] = z;
  float o[CC];
  #pragma unroll
  for (int cc = 0; cc < CC; cc++) o[cc] = b2[cc];
  #pragma unroll
  for (int j = 0; j < HH; j++) {
    float a = b1[j];
    #pragma unroll
    for (int i = 0; i < 15; i++) a += in15[i] * W1[i*HH + j];
    a = fmaxf(a, 0.f);
    #pragma unroll
    for (int cc = 0; cc < CC; cc++) o[cc] += a * W2[j*CC + cc];
  }
  if (valid) {
    #pragma unroll
    for (int cc = 0; cc < CC; cc++) sh_out[(size_t)p*CC + cc] = o[cc];
  }
}

extern "C" void kernel_launch(void* const* d_in, const int* in_sizes, int n_in,
                              void* d_out, int out_size, void* d_ws, size_t ws_size,
                              hipStream_t stream) {
  const float* probe_pos = (const float*)d_in[0];
  const float* mu        = (const float*)d_in[1];
  const float* log_s     = (const float*)d_in[2];
  const float* q         = (const float*)d_in[3];
  const float* F         = (const float*)d_in[4];
  const float* W1        = (const float*)d_in[5];
  const float* b1        = (const float*)d_in[6];
  const float* W2        = (const float*)d_in[7];
  const float* b2        = (const float*)d_in[8];
  const int N = in_sizes[0] / 3;

  float* A = (float*)d_ws;                    // 256*32 floats = 32 KB scratch
  float* sh_out  = (float*)d_out;             // [N,9]
  float* lat_out = sh_out + (size_t)N*CC;     // [N,12]
  float* w_out   = lat_out + (size_t)N*DD;    // [N,256]

  gp_precompute<<<1, 256, 0, stream>>>(mu, log_s, q, F, A);
  const int nblocks = (N + 255) / 256;
  gp_main<<<nblocks, 256, 0, stream>>>(probe_pos, A, W1, b1, W2, b2,
                                       sh_out, lat_out, w_out, N);
}

// Round 2
// 688.963 us; speedup vs baseline: 1.0492x; 1.0492x over previous
//
#include <hip/hip_runtime.h>

#define KG 256      // gaussians
#define DD 12       // feature dim
#define HH 32       // hidden
#define CC 9        // output channels
#define PB 64       // probes per block in main kernel

// ---------------- DPP wave reduction: sum of all 64 lanes lands in lane 63 ----
__device__ __forceinline__ float wave_reduce_sum63(float f) {
  int t;
  t = __builtin_amdgcn_update_dpp(0, __float_as_int(f), 0x111, 0xf, 0xf, true); f += __int_as_float(t); // row_shr:1
  t = __builtin_amdgcn_update_dpp(0, __float_as_int(f), 0x112, 0xf, 0xf, true); f += __int_as_float(t); // row_shr:2
  t = __builtin_amdgcn_update_dpp(0, __float_as_int(f), 0x114, 0xf, 0xf, true); f += __int_as_float(t); // row_shr:4
  t = __builtin_amdgcn_update_dpp(0, __float_as_int(f), 0x118, 0xf, 0xf, true); f += __int_as_float(t); // row_shr:8
  t = __builtin_amdgcn_update_dpp(0, __float_as_int(f), 0x142, 0xa, 0xf, true); f += __int_as_float(t); // row_bcast:15 -> rows 1,3
  t = __builtin_amdgcn_update_dpp(0, __float_as_int(f), 0x143, 0xc, 0xf, true); f += __int_as_float(t); // row_bcast:31 -> rows 2,3
  return f;  // lane 63 holds the full 64-lane sum
}

// ---------------- precompute: per-gaussian coefficient SoA ----------------
// P[f][k], f=0..14: {xx,yy,zz,xy,xz,yz,x,y,z,const} mahal-poly (pre-scaled by
// -0.5*log2e), {x,y,z,const} of dist2, r^2.   Fs[j][k] = F[k][j].
__global__ __launch_bounds__(256) void gp_pre(
    const float* __restrict__ mu, const float* __restrict__ log_s,
    const float* __restrict__ q, const float* __restrict__ F,
    float* __restrict__ P, float* __restrict__ Fs) {
  int k = threadIdx.x;
  if (k >= KG) return;
  float qw = q[k*4+0], qx = q[k*4+1], qy = q[k*4+2], qz = q[k*4+3];
  float nrm = sqrtf(qw*qw + qx*qx + qy*qy + qz*qz);
  float isn = 1.0f / (nrm + 1e-8f);
  qw *= isn; qx *= isn; qy *= isn; qz *= isn;
  float R00 = 1.f - 2.f*(qy*qy + qz*qz);
  float R01 = 2.f*(qx*qy - qw*qz);
  float R02 = 2.f*(qx*qz + qw*qy);
  float R10 = 2.f*(qx*qy + qw*qz);
  float R11 = 1.f - 2.f*(qx*qx + qz*qz);
  float R12 = 2.f*(qy*qz - qw*qx);
  float R20 = 2.f*(qx*qz - qw*qy);
  float R21 = 2.f*(qy*qz + qw*qx);
  float R22 = 1.f - 2.f*(qx*qx + qy*qy);
  float s0 = expf(log_s[k*3+0]);
  float s1 = expf(log_s[k*3+1]);
  float s2 = expf(log_s[k*3+2]);
  float si0 = 1.f/(s0*s0 + 1e-8f);
  float si1 = 1.f/(s1*s1 + 1e-8f);
  float si2 = 1.f/(s2*s2 + 1e-8f);
  float P00 = R00*si0*R00 + R01*si1*R01 + R02*si2*R02;
  float P01 = R00*si0*R10 + R01*si1*R11 + R02*si2*R12;
  float P02 = R00*si0*R20 + R01*si1*R21 + R02*si2*R22;
  float P11 = R10*si0*R10 + R11*si1*R11 + R12*si2*R12;
  float P12 = R10*si0*R20 + R11*si1*R21 + R12*si2*R22;
  float P22 = R20*si0*R20 + R21*si1*R21 + R22*si2*R22;
  float m0 = mu[k*3+0], m1 = mu[k*3+1], m2 = mu[k*3+2];
  float b0 = P00*m0 + P01*m1 + P02*m2;
  float b1v = P01*m0 + P11*m1 + P12*m2;
  float b2v = P02*m0 + P12*m1 + P22*m2;
  float c = m0*b0 + m1*b1v + m2*b2v;
  const float f = -0.7213475204444817f;  // -0.5*log2(e)
  P[ 0*KG+k] = f*P00;  P[ 1*KG+k] = f*P11;  P[ 2*KG+k] = f*P22;
  P[ 3*KG+k] = 2.f*f*P01; P[ 4*KG+k] = 2.f*f*P02; P[ 5*KG+k] = 2.f*f*P12;
  P[ 6*KG+k] = -2.f*f*b0; P[ 7*KG+k] = -2.f*f*b1v; P[ 8*KG+k] = -2.f*f*b2v;
  P[ 9*KG+k] = f*c;
  P[10*KG+k] = -2.f*m0; P[11*KG+k] = -2.f*m1; P[12*KG+k] = -2.f*m2;
  P[13*KG+k] = m0*m0 + m1*m1 + m2*m2;
  float smax = fmaxf(s0, fmaxf(s1, s2));
  P[14*KG+k] = (3.f*smax)*(3.f*smax);
  #pragma unroll
  for (int d = 0; d < DD; d++) Fs[d*KG+k] = F[k*DD+d];
}

// ---------------- main: thread = gaussian k, block = 64 probes -------------
__global__ __launch_bounds__(256) void gp_main(
    const float* __restrict__ pos, const float* __restrict__ P,
    float* __restrict__ w_out, int N) {
  __shared__ float monoLDS[PB*12];
  __shared__ float partLDS[PB*4];
  __shared__ float invLDS[PB];
  const int tid = threadIdx.x;
  const int lane = tid & 63;
  const int wid = tid >> 6;
  const int pbase = blockIdx.x * PB;

  // phase 0: 64 probes' monomials -> LDS  {xx,yy,zz,xy | xz,yz,x,y | z,s3,-,-}
  if (tid < PB) {
    int p = pbase + tid; if (p > N-1) p = N-1;
    float x = pos[p*3+0], y = pos[p*3+1], z = pos[p*3+2];
    float4* m = (float4*)(monoLDS + tid*12);
    m[0] = make_float4(x*x, y*y, z*z, x*y);
    m[1] = make_float4(x*z, y*z, x, y);
    m[2] = make_float4(z, x*x + y*y + z*z, 0.f, 0.f);
  }
  // per-thread gaussian coefficients, loaded once (coalesced SoA)
  float ap[15];
  #pragma unroll
  for (int f = 0; f < 15; f++) ap[f] = P[f*KG + tid];
  __syncthreads();

  // phase 1: g for 64 probes, kept in VGPRs
  float g[PB];
  #pragma unroll
  for (int p = 0; p < PB; p++) {
    const float4 m0 = *(const float4*)(monoLDS + p*12 + 0);
    const float4 m1 = *(const float4*)(monoLDS + p*12 + 4);
    const float4 m2 = *(const float4*)(monoLDS + p*12 + 8);
    float tp = ap[9] + ap[0]*m0.x + ap[1]*m0.y + ap[2]*m0.z + ap[3]*m0.w
             + ap[4]*m1.x + ap[5]*m1.y + ap[6]*m1.z + ap[7]*m1.w + ap[8]*m2.x;
    float d2 = m2.y + ap[13] + ap[10]*m1.z + ap[11]*m1.w + ap[12]*m2.x;
    g[p] = (d2 < ap[14]) ? __builtin_amdgcn_exp2f(tp) : 0.f;
  }

  // phase 2: per-probe sum over the 256 gaussians (DPP + cross-wave LDS)
  #pragma unroll
  for (int p = 0; p < PB; p++) {
    float s = wave_reduce_sum63(g[p]);
    if (lane == 63) partLDS[p*4 + wid] = s;
  }
  __syncthreads();
  if (tid < PB) {
    float4 s4 = *(float4*)(partLDS + tid*4);
    invLDS[tid] = 1.f / (s4.x + s4.y + s4.z + s4.w + 1e-8f);
  }
  __syncthreads();

  // phase 3: normalize + coalesced store (lane=t -> contiguous k)
  float* wrow = w_out + (size_t)pbase*KG + tid;
  if (pbase + PB <= N) {
    #pragma unroll
    for (int p4 = 0; p4 < PB/4; p4++) {
      float4 iv = *(float4*)(invLDS + p4*4);
      wrow[(size_t)(p4*4+0)*KG] = g[p4*4+0]*iv.x;
      wrow[(size_t)(p4*4+1)*KG] = g[p4*4+1]*iv.y;
      wrow[(size_t)(p4*4+2)*KG] = g[p4*4+2]*iv.z;
      wrow[(size_t)(p4*4+3)*KG] = g[p4*4+3]*iv.w;
    }
  } else {
    #pragma unroll
    for (int p4 = 0; p4 < PB/4; p4++) {
      float4 iv = *(float4*)(invLDS + p4*4);
      if (pbase+p4*4+0 < N) wrow[(size_t)(p4*4+0)*KG] = g[p4*4+0]*iv.x;
      if (pbase+p4*4+1 < N) wrow[(size_t)(p4*4+1)*KG] = g[p4*4+1]*iv.y;
      if (pbase+p4*4+2 < N) wrow[(size_t)(p4*4+2)*KG] = g[p4*4+2]*iv.z;
      if (pbase+p4*4+3 < N) wrow[(size_t)(p4*4+3)*KG] = g[p4*4+3]*iv.w;
    }
  }
}

// ---------------- latent: wave per probe, coalesced w re-read --------------
__global__ __launch_bounds__(256) void gp_latent(
    const float* __restrict__ w_out, const float* __restrict__ Fs,
    float* __restrict__ lat_out, int N) {
  const int lane = threadIdx.x & 63;
  const int wid = threadIdx.x >> 6;
  const int p = blockIdx.x*4 + wid;
  if (p >= N) return;
  const float4 w4 = *(const float4*)(w_out + (size_t)p*KG + lane*4);
  float s[DD];
  #pragma unroll
  for (int j = 0; j < DD; j++) {
    const float4 f4 = *(const float4*)(Fs + j*KG + lane*4);
    float d = w4.x*f4.x + w4.y*f4.y + w4.z*f4.z + w4.w*f4.w;
    s[j] = wave_reduce_sum63(d);
  }
  if (lane == 63) {
    float4* lp = (float4*)(lat_out + (size_t)p*DD);
    lp[0] = make_float4(s[0], s[1], s[2],  s[3]);
    lp[1] = make_float4(s[4], s[5], s[6],  s[7]);
    lp[2] = make_float4(s[8], s[9], s[10], s[11]);
  }
}

// ---------------- MLP: thread per probe ------------------------------------
__global__ __launch_bounds__(256) void gp_mlp(
    const float* __restrict__ pos, const float* __restrict__ lat,
    const float* __restrict__ W1, const float* __restrict__ b1,
    const float* __restrict__ W2, const float* __restrict__ b2,
    float* __restrict__ sh_out, int N) {
  int p = blockIdx.x*256 + threadIdx.x;
  if (p >= N) return;
  const float4* lp = (const float4*)(lat + (size_t)p*DD);
  float4 a = lp[0], b = lp[1], c = lp[2];
  float in15[15] = {a.x,a.y,a.z,a.w, b.x,b.y,b.z,b.w, c.x,c.y,c.z,c.w,
                    pos[p*3+0], pos[p*3+1], pos[p*3+2]};
  float o[CC];
  #pragma unroll
  for (int cc = 0; cc < CC; cc++) o[cc] = b2[cc];
  #pragma unroll
  for (int j = 0; j < HH; j++) {
    float acc = b1[j];
    #pragma unroll
    for (int i = 0; i < 15; i++) acc += in15[i] * W1[i*HH + j];
    acc = fmaxf(acc, 0.f);
    #pragma unroll
    for (int cc = 0; cc < CC; cc++) o[cc] += acc * W2[j*CC + cc];
  }
  #pragma unroll
  for (int cc = 0; cc < CC; cc++) sh_out[(size_t)p*CC + cc] = o[cc];
}

extern "C" void kernel_launch(void* const* d_in, const int* in_sizes, int n_in,
                              void* d_out, int out_size, void* d_ws, size_t ws_size,
                              hipStream_t stream) {
  const float* probe_pos = (const float*)d_in[0];
  const float* mu        = (const float*)d_in[1];
  const float* log_s     = (const float*)d_in[2];
  const float* q         = (const float*)d_in[3];
  const float* F         = (const float*)d_in[4];
  const float* W1        = (const float*)d_in[5];
  const float* b1        = (const float*)d_in[6];
  const float* W2        = (const float*)d_in[7];
  const float* b2        = (const float*)d_in[8];
  const int N = in_sizes[0] / 3;

  float* P  = (float*)d_ws;        // 15*256 floats
  float* Fs = P + 15*KG;           // 12*256 floats (total 27 KB scratch)
  float* sh_out  = (float*)d_out;              // [N,9]
  float* lat_out = sh_out + (size_t)N*CC;      // [N,12]
  float* w_out   = lat_out + (size_t)N*DD;     // [N,256]

  gp_pre<<<1, 256, 0, stream>>>(mu, log_s, q, F, P, Fs);
  gp_main<<<(N + PB - 1)/PB, 256, 0, stream>>>(probe_pos, P, w_out, N);
  gp_latent<<<(N + 3)/4, 256, 0, stream>>>(w_out, Fs, lat_out, N);
  gp_mlp<<<(N + 255)/256, 256, 0, stream>>>(probe_pos, lat_out, W1, b1, W2, b2, sh_out, N);
}

// Round 3
// 492.042 us; speedup vs baseline: 1.4690x; 1.4002x over previous
//
#include <hip/hip_runtime.h>

#define KG 256      // gaussians
#define DD 12       // feature dim
#define HH 32       // hidden
#define CC 9        // output channels
#define PB 16       // probes per block
#define WST 260     // LDS row stride (pad vs 256: breaks pow2 bank aliasing)

// ---------------- precompute: per-gaussian coefficient SoA ----------------
// P[f][k], f=0..14: {xx,yy,zz,xy,xz,yz,x,y,z,const} mahal-poly (pre-scaled by
// -0.5*log2e), {x,y,z,const} of dist2, r^2.   Fs[j][k] = F[k][j].
__global__ __launch_bounds__(256) void gp_pre(
    const float* __restrict__ mu, const float* __restrict__ log_s,
    const float* __restrict__ q, const float* __restrict__ F,
    float* __restrict__ P, float* __restrict__ Fs) {
  int k = threadIdx.x;
  if (k >= KG) return;
  float qw = q[k*4+0], qx = q[k*4+1], qy = q[k*4+2], qz = q[k*4+3];
  float nrm = sqrtf(qw*qw + qx*qx + qy*qy + qz*qz);
  float isn = 1.0f / (nrm + 1e-8f);
  qw *= isn; qx *= isn; qy *= isn; qz *= isn;
  float R00 = 1.f - 2.f*(qy*qy + qz*qz);
  float R01 = 2.f*(qx*qy - qw*qz);
  float R02 = 2.f*(qx*qz + qw*qy);
  float R10 = 2.f*(qx*qy + qw*qz);
  float R11 = 1.f - 2.f*(qx*qx + qz*qz);
  float R12 = 2.f*(qy*qz - qw*qx);
  float R20 = 2.f*(qx*qz - qw*qy);
  float R21 = 2.f*(qy*qz + qw*qx);
  float R22 = 1.f - 2.f*(qx*qx + qy*qy);
  float s0 = expf(log_s[k*3+0]);
  float s1 = expf(log_s[k*3+1]);
  float s2 = expf(log_s[k*3+2]);
  float si0 = 1.f/(s0*s0 + 1e-8f);
  float si1 = 1.f/(s1*s1 + 1e-8f);
  float si2 = 1.f/(s2*s2 + 1e-8f);
  float P00 = R00*si0*R00 + R01*si1*R01 + R02*si2*R02;
  float P01 = R00*si0*R10 + R01*si1*R11 + R02*si2*R12;
  float P02 = R00*si0*R20 + R01*si1*R21 + R02*si2*R22;
  float P11 = R10*si0*R10 + R11*si1*R11 + R12*si2*R12;
  float P12 = R10*si0*R20 + R11*si1*R21 + R12*si2*R22;
  float P22 = R20*si0*R20 + R21*si1*R21 + R22*si2*R22;
  float m0 = mu[k*3+0], m1 = mu[k*3+1], m2 = mu[k*3+2];
  float b0 = P00*m0 + P01*m1 + P02*m2;
  float b1v = P01*m0 + P11*m1 + P12*m2;
  float b2v = P02*m0 + P12*m1 + P22*m2;
  float c = m0*b0 + m1*b1v + m2*b2v;
  const float f = -0.7213475204444817f;  // -0.5*log2(e)
  P[ 0*KG+k] = f*P00;  P[ 1*KG+k] = f*P11;  P[ 2*KG+k] = f*P22;
  P[ 3*KG+k] = 2.f*f*P01; P[ 4*KG+k] = 2.f*f*P02; P[ 5*KG+k] = 2.f*f*P12;
  P[ 6*KG+k] = -2.f*f*b0; P[ 7*KG+k] = -2.f*f*b1v; P[ 8*KG+k] = -2.f*f*b2v;
  P[ 9*KG+k] = f*c;
  P[10*KG+k] = -2.f*m0; P[11*KG+k] = -2.f*m1; P[12*KG+k] = -2.f*m2;
  P[13*KG+k] = m0*m0 + m1*m1 + m2*m2;
  float smax = fmaxf(s0, fmaxf(s1, s2));
  P[14*KG+k] = (3.f*smax)*(3.f*smax);
  #pragma unroll
  for (int d = 0; d < DD; d++) Fs[d*KG+k] = F[k*DD+d];
}

// ---------------- fused: g -> (w, latent, sh) in one kernel ----------------
// thread = gaussian k for phases 1/3; thread = (probe,feature) for dots.
__global__ __launch_bounds__(256) void gp_fused(
    const float* __restrict__ pos, const float* __restrict__ P,
    const float* __restrict__ Fs,
    const float* __restrict__ W1, const float* __restrict__ b1,
    const float* __restrict__ W2, const float* __restrict__ b2,
    float* __restrict__ sh_out, float* __restrict__ lat_out,
    float* __restrict__ w_out, int N) {
  __shared__ float wL[PB*WST];        // 16.6 KB: unnormalized g, [p][k]
  __shared__ float fL[(DD+1)*WST];    // 13.5 KB: F rows + ones row (denominator)
  __shared__ float monoL[PB*12];      // probe monomials
  __shared__ float dotL[PB*13];       // 12 latent dots + denom per probe
  __shared__ float invL[PB];
  const int tid = threadIdx.x;
  const int pbase = blockIdx.x * PB;

  // ---- stage F (coalesced, L2-hot) + ones row + probe monomials ----
  #pragma unroll
  for (int j = 0; j < DD; j++) fL[j*WST + tid] = Fs[j*KG + tid];
  fL[DD*WST + tid] = 1.0f;
  if (tid < PB) {
    int p = pbase + tid; if (p >= N) p = N - 1;
    float x = pos[p*3+0], y = pos[p*3+1], z = pos[p*3+2];
    float* m = monoL + tid*12;
    m[0]=x*x; m[1]=y*y; m[2]=z*z; m[3]=x*y; m[4]=x*z; m[5]=y*z;
    m[6]=x; m[7]=y; m[8]=z; m[9]=x*x+y*y+z*z; m[10]=0.f; m[11]=0.f;
  }
  // per-thread gaussian coefficients, loaded once (coalesced SoA)
  float ap[15];
  #pragma unroll
  for (int f = 0; f < 15; f++) ap[f] = P[f*KG + tid];
  __syncthreads();

  // ---- phase 1: g for 16 probes (registers) + transpose into LDS ----
  float g[PB];
  #pragma unroll
  for (int p = 0; p < PB; p++) {
    const float4 m0 = *(const float4*)(monoL + p*12 + 0);
    const float4 m1 = *(const float4*)(monoL + p*12 + 4);
    const float4 m2 = *(const float4*)(monoL + p*12 + 8);
    float tp = ap[9] + ap[0]*m0.x + ap[1]*m0.y + ap[2]*m0.z + ap[3]*m0.w
             + ap[4]*m1.x + ap[5]*m1.y + ap[6]*m1.z + ap[7]*m1.w + ap[8]*m2.x;
    float d2 = m2.y + ap[13] + ap[10]*m1.z + ap[11]*m1.w + ap[12]*m2.x;
    float gv = (d2 < ap[14]) ? exp2f(tp) : 0.f;
    g[p] = gv;
    wL[p*WST + tid] = gv;           // bank = (4p + tid)%32 -> 2-way, free
  }
  __syncthreads();

  // ---- phase 2: 13 dots per probe (12 latent + denom via ones row) ----
  if (tid < PB*13) {
    const int p = tid / 13, j = tid - p*13;
    const float* wr = wL + p*WST;   // 13-lane broadcast groups, p-quads distinct
    const float* fr = fL + j*WST;   // <=2 addrs per bank quad -> free
    float4 a4 = make_float4(0.f, 0.f, 0.f, 0.f);
    #pragma unroll 8
    for (int k = 0; k < KG; k += 4) {
      const float4 wv = *(const float4*)(wr + k);
      const float4 fv = *(const float4*)(fr + k);
      a4.x += wv.x*fv.x; a4.y += wv.y*fv.y;
      a4.z += wv.z*fv.z; a4.w += wv.w*fv.w;
    }
    dotL[tid] = (a4.x + a4.y) + (a4.z + a4.w);
  }
  __syncthreads();
  if (tid < PB) invL[tid] = 1.0f / (dotL[tid*13 + 12] + 1e-8f);
  __syncthreads();

  // ---- phase 3: normalized w stores (lane=k -> 256B contiguous per wave) ----
  float* wrow = w_out + (size_t)pbase*KG + tid;
  #pragma unroll
  for (int p = 0; p < PB; p++) {
    if (pbase + p < N) wrow[(size_t)p*KG] = g[p] * invL[p];
  }
  // ---- latent stores (192 consecutive floats) ----
  if (tid < PB*DD) {
    const int p = tid / DD, j = tid - p*DD;
    if (pbase + p < N)
      lat_out[(size_t)pbase*DD + tid] = dotL[p*13 + j] * invL[p];
  }
  // ---- fused MLP: thread per probe (W1/W2 uniform -> scalar loads) ----
  if (tid < PB && pbase + tid < N) {
    const int p = tid;
    const float inv = invL[p];
    float in15[15];
    #pragma unroll
    for (int j = 0; j < DD; j++) in15[j] = dotL[p*13 + j] * inv;
    in15[12] = monoL[p*12+6]; in15[13] = monoL[p*12+7]; in15[14] = monoL[p*12+8];
    float o[CC];
    #pragma unroll
    for (int cc = 0; cc < CC; cc++) o[cc] = b2[cc];
    #pragma unroll
    for (int j = 0; j < HH; j++) {
      float a = b1[j];
      #pragma unroll
      for (int i = 0; i < 15; i++) a += in15[i] * W1[i*HH + j];
      a = fmaxf(a, 0.f);
      #pragma unroll
      for (int cc = 0; cc < CC; cc++) o[cc] += a * W2[j*CC + cc];
    }
    #pragma unroll
    for (int cc = 0; cc < CC; cc++)
      sh_out[(size_t)(pbase + p)*CC + cc] = o[cc];
  }
}

extern "C" void kernel_launch(void* const* d_in, const int* in_sizes, int n_in,
                              void* d_out, int out_size, void* d_ws, size_t ws_size,
                              hipStream_t stream) {
  const float* probe_pos = (const float*)d_in[0];
  const float* mu        = (const float*)d_in[1];
  const float* log_s     = (const float*)d_in[2];
  const float* q         = (const float*)d_in[3];
  const float* F         = (const float*)d_in[4];
  const float* W1        = (const float*)d_in[5];
  const float* b1        = (const float*)d_in[6];
  const float* W2        = (const float*)d_in[7];
  const float* b2        = (const float*)d_in[8];
  const int N = in_sizes[0] / 3;

  float* P  = (float*)d_ws;        // 15*256 floats
  float* Fs = P + 15*KG;           // 12*256 floats
  float* sh_out  = (float*)d_out;              // [N,9]
  float* lat_out = sh_out + (size_t)N*CC;      // [N,12]
  float* w_out   = lat_out + (size_t)N*DD;     // [N,256]

  gp_pre<<<1, 256, 0, stream>>>(mu, log_s, q, F, P, Fs);
  const int nb = (N + PB - 1) / PB;
  gp_fused<<<nb, 256, 0, stream>>>(probe_pos, P, Fs, W1, b1, W2, b2,
                                   sh_out, lat_out, w_out, N);
}